// Round 5
// baseline (25106.898 us; speedup 1.0000x reference)
//
#include <hip/hip_runtime.h>

#define B_ 4096
#define L_ 15
#define NSTEP_ 5
#define VOC_ 30005
#define PAD_ 30003

typedef _Float16 f16;
typedef f16  f16x8 __attribute__((ext_vector_type(8)));
typedef f16  f16x4 __attribute__((ext_vector_type(4)));
typedef float f32x16 __attribute__((ext_vector_type(16)));

#if defined(__has_builtin)
#if __has_builtin(__builtin_amdgcn_global_load_lds)
#define HAS_GLL 1
#endif
#endif

__device__ __forceinline__ float sigf(float x){ return 1.0f/(1.0f+expf(-x)); }

#ifdef HAS_GLL
__device__ __forceinline__ void gll16(const f16* g, f16* l){
  __builtin_amdgcn_global_load_lds(
      (const __attribute__((address_space(1))) void*)g,
      (__attribute__((address_space(3))) void*)l, 16, 0, 0);
}
#endif

// ---------------------------------------------------------------- params
struct RecParams {
  const f16 *A1h_0,*A1l_0,*A1h_1,*A1l_1;
  const f16 *A2h_0,*A2l_0,*A2h_1,*A2l_1;
  const f16 *Wh_0,*Wl_0,*Wh_1,*Wl_1;
  const float *bias_0,*bias_1;
  float *c_0,*c_1,*h2_0,*h2_1;
  f16 *hh_0,*hl_0,*hh_1,*hl_1;
  int lda1, lda2, ldw, ldh, ldh2, k1t, k2t, first, act0, act1;
};

// swizzled byte offset into a [128 rows][16 k] f16 (4KB) LDS array.
// unit u = 2r+s (r=row&7) -> u' = u ^ (u>>1)  (4-bit Gray encode): bijective,
// spreads same-s reads across 8 distinct 16B slots -> near-conflict-free b128.
__device__ __forceinline__ int swz(int row, int s){
  int u = ((row&7)<<1) | s;
  return ((row>>3)<<8) + ((u ^ (u>>1))<<4);
}

// ------------------------------------------------- fused split-f16 MFMA GEMM + LSTM cell
// C(Bc x 2048) = A(Bc x K) @ W^T (+bias); A,W given as (hi, lo*2^12) f16 pairs.
// W rows permuted as n*4+gate. 3 MFMA passes: accM += Ah*Wh; accX += Ah*Wl + Al*Wh;
// z = accM + 2^-12 accX + bias -> LSTM cell in epilogue (via LDS regroup).
// Staging: global_load_lds dwordx4 into LINEAR LDS; the Gray swizzle is applied
// to the per-lane GLOBAL source address (inverse permutation), so LDS content
// matches swz() and the ds_read side is unchanged.
__global__ __launch_bounds__(256,2) void rec_gemm(RecParams p){
  const int dir = blockIdx.z;
  if (!(dir ? p.act1 : p.act0)) return;
  const f16* A1h = dir ? p.A1h_1 : p.A1h_0;
  const f16* A1l = dir ? p.A1l_1 : p.A1l_0;
  const f16* A2h = dir ? p.A2h_1 : p.A2h_0;
  const f16* A2l = dir ? p.A2l_1 : p.A2l_0;
  const f16* Wh  = dir ? p.Wh_1  : p.Wh_0;
  const f16* Wl  = dir ? p.Wl_1  : p.Wl_0;
  const float* bias = dir ? p.bias_1 : p.bias_0;
  float* cbuf = dir ? p.c_1 : p.c_0;
  float* h2   = dir ? p.h2_1 : p.h2_0;
  f16* hhb = dir ? p.hh_1 : p.hh_0;
  f16* hlb = dir ? p.hl_1 : p.hl_0;

  const int tid  = threadIdx.x;
  const int lane = tid & 63;
  const int w    = tid >> 6;
  const int mbase = blockIdx.y*128, nbase = blockIdx.x*128;

  __shared__ union {
    float z[128*128];          // 64 KB epilogue
    f16   stg[8][2048];        // [buf*4 + {Ah,Al,Bh,Bl}] 4KB each (32 KB)
  } sm;

  f32x16 accM[2][2], accX[2][2];
#pragma unroll
  for (int i=0;i<2;i++)
#pragma unroll
    for (int j=0;j<2;j++)
#pragma unroll
      for (int r=0;r<16;r++){ accM[i][j][r]=0.f; accX[i][j][r]=0.f; }

  // fragment read offsets (swizzled, unchanged from validated R4)
  const int arow = (w&1)*64 + (lane&31);
  const int brow = (w>>1)*64 + (lane&31);
  const int fs = lane>>5;
  const int aoff0 = swz(arow,    fs), aoff1 = swz(arow+32, fs);
  const int boff0 = swz(brow,    fs), boff1 = swz(brow+32, fs);

  const int ktot = p.k1t + p.k2t;

#ifdef HAS_GLL
  // staging source mapping: wave w fills LDS units [w*64, w*64+64); lane i's
  // global (row,s) = Gray-decode of (unit&15) within group (unit>>4).
  const int Uq = (w<<6) + lane;
  int ug = Uq & 15; ug ^= ug >> 1; ug ^= ug >> 2;      // 4-bit Gray decode
  const int rowS = ((Uq>>4)<<3) + (ug>>1);
  const int sS   = ug & 1;
  const long offA1 = (long)(mbase+rowS)*p.lda1 + sS*8;
  const long offA2 = (long)(mbase+rowS)*p.lda2 + sS*8;
  const long offB  = (long)(nbase+rowS)*p.ldw  + sS*8;

  auto stage = [&](int buf, int kt){
    const f16 *ah, *al; long ao;
    if (kt < p.k1t){ ah=A1h; al=A1l; ao = offA1 + (long)kt*16; }
    else           { ah=A2h; al=A2l; ao = offA2 + (long)(kt-p.k1t)*16; }
    long bo = offB + (long)kt*16;
    gll16(ah + ao, &sm.stg[buf*4+0][w<<9]);
    gll16(al + ao, &sm.stg[buf*4+1][w<<9]);
    gll16(Wh + bo, &sm.stg[buf*4+2][w<<9]);
    gll16(Wl + bo, &sm.stg[buf*4+3][w<<9]);
  };

  stage(0, 0);
  __syncthreads();
#else
  // fallback: register staging (R4 path)
  const int srow = tid >> 1, ss = tid & 1;
  const int sws = swz(srow, ss);
  f16x8 ra_h, ra_l, rb_h, rb_l;
  auto gload = [&](int kt){
    const f16 *ah, *al; int lda, kc;
    if (kt < p.k1t){ ah=A1h; al=A1l; lda=p.lda1; kc=kt*16; }
    else           { ah=A2h; al=A2l; lda=p.lda2; kc=(kt-p.k1t)*16; }
    size_t ao = (size_t)(mbase+srow)*lda + kc + ss*8;
    ra_h = *(const f16x8*)(ah + ao);
    ra_l = *(const f16x8*)(al + ao);
    size_t bo = (size_t)(nbase+srow)*p.ldw + kt*16 + ss*8;
    rb_h = *(const f16x8*)(Wh + bo);
    rb_l = *(const f16x8*)(Wl + bo);
  };
  auto swrite = [&](int buf){
    *(f16x8*)((char*)sm.stg[buf*4+0] + sws) = ra_h;
    *(f16x8*)((char*)sm.stg[buf*4+1] + sws) = ra_l;
    *(f16x8*)((char*)sm.stg[buf*4+2] + sws) = rb_h;
    *(f16x8*)((char*)sm.stg[buf*4+3] + sws) = rb_l;
  };
  gload(0); swrite(0);
  if (ktot > 1) gload(1);
  __syncthreads();
#endif

  for (int kt=0; kt<ktot; ++kt){
    const int cur = kt & 1;
#ifdef HAS_GLL
    if (kt+1 < ktot) stage((kt+1)&1, kt+1);   // DMA flies during compute
#endif
    const char* Ah_b = (const char*)sm.stg[cur*4+0];
    const char* Al_b = (const char*)sm.stg[cur*4+1];
    const char* Bh_b = (const char*)sm.stg[cur*4+2];
    const char* Bl_b = (const char*)sm.stg[cur*4+3];
    f16x8 a0h = *(const f16x8*)(Ah_b + aoff0);
    f16x8 a1h = *(const f16x8*)(Ah_b + aoff1);
    f16x8 a0l = *(const f16x8*)(Al_b + aoff0);
    f16x8 a1l = *(const f16x8*)(Al_b + aoff1);
    f16x8 b0h = *(const f16x8*)(Bh_b + boff0);
    f16x8 b1h = *(const f16x8*)(Bh_b + boff1);
    f16x8 b0l = *(const f16x8*)(Bl_b + boff0);
    f16x8 b1l = *(const f16x8*)(Bl_b + boff1);

    accM[0][0] = __builtin_amdgcn_mfma_f32_32x32x16_f16(a0h, b0h, accM[0][0], 0,0,0);
    accX[0][0] = __builtin_amdgcn_mfma_f32_32x32x16_f16(a0h, b0l, accX[0][0], 0,0,0);
    accX[0][0] = __builtin_amdgcn_mfma_f32_32x32x16_f16(a0l, b0h, accX[0][0], 0,0,0);
    accM[1][0] = __builtin_amdgcn_mfma_f32_32x32x16_f16(a1h, b0h, accM[1][0], 0,0,0);
    accX[1][0] = __builtin_amdgcn_mfma_f32_32x32x16_f16(a1h, b0l, accX[1][0], 0,0,0);
    accX[1][0] = __builtin_amdgcn_mfma_f32_32x32x16_f16(a1l, b0h, accX[1][0], 0,0,0);
    accM[0][1] = __builtin_amdgcn_mfma_f32_32x32x16_f16(a0h, b1h, accM[0][1], 0,0,0);
    accX[0][1] = __builtin_amdgcn_mfma_f32_32x32x16_f16(a0h, b1l, accX[0][1], 0,0,0);
    accX[0][1] = __builtin_amdgcn_mfma_f32_32x32x16_f16(a0l, b1h, accX[0][1], 0,0,0);
    accM[1][1] = __builtin_amdgcn_mfma_f32_32x32x16_f16(a1h, b1h, accM[1][1], 0,0,0);
    accX[1][1] = __builtin_amdgcn_mfma_f32_32x32x16_f16(a1h, b1l, accX[1][1], 0,0,0);
    accX[1][1] = __builtin_amdgcn_mfma_f32_32x32x16_f16(a1l, b1h, accX[1][1], 0,0,0);

#ifndef HAS_GLL
    if (kt+1 < ktot){
      swrite((kt+1)&1);
      if (kt+2 < ktot) gload(kt+2);
    }
#endif
    __syncthreads();
  }

  // ---- epilogue: z tiles -> LDS (regroup gates), then fused LSTM cell
#pragma unroll
  for (int tm=0;tm<2;tm++)
#pragma unroll
   for (int tn=0;tn<2;tn++){
    int lcol = (w>>1)*64 + tn*32 + (lane&31);
    float bv = bias[nbase + lcol];
#pragma unroll
    for (int r=0;r<16;r++){
      int lrow = (w&1)*64 + tm*32 + (r&3) + 8*(r>>2) + 4*(lane>>5);
      sm.z[lrow*128 + lcol] = accM[tm][tn][r] + 0.000244140625f*accX[tm][tn][r] + bv;
    }
   }
  __syncthreads();

  const int nb = blockIdx.x*32;   // hidden-unit base for this block
#pragma unroll
  for (int it=0; it<16; ++it){
    int idx = it*256 + tid;
    int nq = idx & 31, row = idx >> 5;
    float4 g4 = *(const float4*)&sm.z[row*128 + nq*4];
    int m = mbase + row, n = nb + nq;
    float cp = p.first ? 0.f : cbuf[(size_t)m*512 + n];
    float cc = sigf(g4.y)*cp + sigf(g4.x)*tanhf(g4.z);
    float hv = sigf(g4.w)*tanhf(cc);
    cbuf[(size_t)m*512 + n] = cc;
    f16 hi = (f16)hv;
    f16 lo = (f16)((hv - (float)hi)*4096.0f);
    hhb[(size_t)m*p.ldh + n] = hi;
    hlb[(size_t)m*p.ldh + n] = lo;
    if (h2) h2[(size_t)m*p.ldh2 + n] = hv;
  }
}

// ---------------------------------------------------------------- prep (split f16)
__global__ void prep_w0(const float* Wih, const float* Whh, const float* b0,
                        f16* Wph, f16* Wpl, float* bp){
  int gid = blockIdx.x*blockDim.x + threadIdx.x;
  const int TOT = 2*2048*1040;
  if (gid >= TOT) return;
  int k = gid % 1040; int r = gid / 1040;
  int n4g = r & 2047; int dirn = r >> 11;
  int n = n4g >> 2, g = n4g & 3;
  int srow = dirn*2048 + g*512 + n;
  float v;
  if (k < 513)      v = Wih[(size_t)srow*513 + k];
  else if (k < 528) v = 0.f;
  else              v = Whh[(size_t)srow*512 + (k-528)];
  f16 hi = (f16)v;
  Wph[gid] = hi;
  Wpl[gid] = (f16)((v - (float)hi)*4096.0f);
  if (k == 0) bp[r] = b0[srow];
}

__global__ void prep_w1(const float* Wih, const float* Whh, const float* b1,
                        f16* Wph, f16* Wpl, float* bp){
  int gid = blockIdx.x*blockDim.x + threadIdx.x;
  const int TOT = 2*2048*1536;
  if (gid >= TOT) return;
  int k = gid % 1536; int r = gid / 1536;
  int n4g = r & 2047; int dirn = r >> 11;
  int n = n4g >> 2, g = n4g & 3;
  int srow = dirn*2048 + g*512 + n;
  float v;
  if (k < 1024) v = Wih[(size_t)srow*1024 + k];
  else          v = Whh[(size_t)srow*512 + (k-1024)];
  f16 hi = (f16)v;
  Wph[gid] = hi;
  Wpl[gid] = (f16)((v - (float)hi)*4096.0f);
  if (k == 0) bp[r] = b1[srow];
}

__global__ void prep_mlpwt(const float* mW, float* wt){
  int gid = blockIdx.x*blockDim.x + threadIdx.x;
  if (gid >= 100*1040) return;
  int j = gid / 1040, k = gid % 1040;
  wt[k*100 + j] = mW[gid];
}

__global__ __launch_bounds__(128) void prep_encproj(const float* enc, const float* delv,
                        const float* holdv, const float* m1W, const float* m1b, float* ep){
  int r = blockIdx.x;
  __shared__ float row[256];
  const float* src = (r < VOC_) ? enc + (size_t)r*256 : (r == VOC_ ? delv : holdv);
  for (int i=threadIdx.x;i<256;i+=128) row[i]=src[i];
  __syncthreads();
  int j = threadIdx.x;
  if (j < 100){
    double s = (double)m1b[j];
    const float* wr = m1W + (size_t)j*298;
    for (int k=0;k<256;k++) s += (double)wr[k] * (double)row[k];
    ep[(size_t)r*100 + j] = (float)s;
  }
}

__global__ void init_st(const int* ids, const int* seqlen, int* st, int* len){
  int gid = blockIdx.x*blockDim.x + threadIdx.x;
  if (gid < B_*L_) st[gid] = ids[gid];
  if (gid < B_)    len[gid] = seqlen[gid];
}

__global__ void sentinel(float* out, float v){
  int gid = blockIdx.x*blockDim.x + threadIdx.x;
  if (gid < B_*NSTEP_) out[gid] = v;
}

// ---------------------------------------- per-(step,ts) 2-timestep X build (split f16)
__global__ void build_x2(const int* st, const int* ids, const float* emb,
                         f16* X2h, f16* X2l, int pos, int tf, int tb, int b0, int Bc){
  int gid = blockIdx.x*blockDim.x + threadIdx.x;
  if (gid >= 2*Bc*132) return;
  int q = gid % 132; int row = gid / 132;
  int b = row % Bc; int d = row / Bc;
  int t = d ? tb : tf;
  int gb = b0 + b;
  int col = q << 2;
  float4 v = make_float4(0.f,0.f,0.f,0.f);
  if (col < 256){
    if (t != pos) v = *(const float4*)(emb + (size_t)st[gb*L_+t]*256 + col);
  } else if (col < 512){
    v = *(const float4*)(emb + (size_t)ids[gb*L_+t]*256 + (col-256));
  } else if (col == 512){
    v.x = (t==pos) ? 1.f : 0.f;
  }
  f16x4 hi, lo;
  float vv[4] = {v.x, v.y, v.z, v.w};
#pragma unroll
  for (int j=0;j<4;j++){
    f16 h = (f16)vv[j];
    hi[j] = h;
    lo[j] = (f16)((vv[j] - (float)h)*4096.0f);
  }
  *(f16x4*)(X2h + (size_t)row*528 + col) = hi;
  *(f16x4*)(X2l + (size_t)row*528 + col) = lo;
}

// ------------------------------------------------- scoring + sequence edit
__global__ __launch_bounds__(128) void score_update(
    const float* pooled, const float* keypos, const float* mWt, const float* mb,
    const float* ep, const float* m1W, const int* repw, const int* valid,
    int* st, int* len, float* outPis, float* outActs, int step, int pos, int b0){
  int b = blockIdx.x;
  int bg = b0 + b;
  __shared__ float rep[1040];
  __shared__ float r100[100];
  __shared__ double sc[42];
  int tid = threadIdx.x;
  for (int i=tid;i<1024;i+=128) rep[i] = pooled[(size_t)b*1024+i];
  if (tid < 16){
    if (tid == 0) rep[1024] = keypos[bg*L_+pos];
    else          rep[1024+tid] = ((tid-1)==pos) ? 1.f : 0.f;
  }
  __syncthreads();
  if (tid < 100){
    double s = (double)mb[tid];
    for (int k=0;k<1040;k++) s += (double)mWt[k*100+tid] * (double)rep[k];
    r100[tid] = (float)s;
  }
  __syncthreads();
  if (tid < 42){
    int row = (tid < 40) ? repw[((size_t)bg*NSTEP_+step)*40 + tid] : (VOC_ + (tid-40));
    const float* er = ep + (size_t)row*100;
    double s = 0.0;
    for (int j=0;j<100;j++) s += (double)er[j] * (double)r100[j];
    for (int j=0;j<100;j++) s += (double)m1W[j*298 + 256 + tid] * (double)r100[j];
    sc[tid] = s;
  }
  __syncthreads();
  if (tid == 0){
    double mx = sc[0]; int am = 0;
    for (int k=1;k<42;k++) if (sc[k] > mx){ mx = sc[k]; am = k; }
    double sum = 0.0;
    for (int k=0;k<42;k++) sum += exp(sc[k]-mx);
    float pi = (float)(1.0/sum);
    int vid = valid[bg*NSTEP_+step];
    int ln  = len[bg];
    int repb = (am < 20) ? 1 : 0;
    int insb = (am >= 20 && am < 40) ? 1 : 0;
    int delb = (am == 40) ? 1 : 0;
    int repf = repb*vid;
    int insf = insb*vid*(((ln+insb) <= 15) ? 1 : 0);
    int delf = delb*vid*(((ln-delb) >  2) ? 1 : 0);
    int T = L_ - pos;
    int tail[13];
    for (int j=0;j<T;j++) tail[j] = st[bg*L_+pos+j];
    int aw = repw[((size_t)bg*NSTEP_+step)*40 + (am < 20 ? am : 19)];
    for (int j=0;j<T;j++){
      int rv = (j==0) ? aw : tail[j];
      int iv = (j==0) ? aw : tail[j-1];
      int dv = (j < T-1) ? tail[j+1] : PAD_;
      int hv = tail[j];
      int nv = repf ? rv : (insf ? iv : (delf ? dv : hv));
      st[bg*L_+pos+j] = nv;
    }
    len[bg] = ln + insf - delf;
    outPis[bg*NSTEP_+step]  = pi;
    outActs[bg*NSTEP_+step] = (float)am;
  }
}

__global__ void finalize(const int* st, const int* len, float* out){
  int gid = blockIdx.x*blockDim.x + threadIdx.x;
  if (gid < B_*L_)            out[2*B_*NSTEP_ + gid] = (float)st[gid];
  else if (gid < B_*L_ + B_)  out[2*B_*NSTEP_ + B_*L_ + (gid - B_*L_)] = (float)len[gid - B_*L_];
}

// ---------------------------------------------------------------- launch
extern "C" void kernel_launch(void* const* d_in, const int* in_sizes, int n_in,
                              void* d_out, int out_size, void* d_ws, size_t ws_size,
                              hipStream_t stream) {
  const int*   ids    = (const int*)  d_in[0];
  const float* keypos = (const float*)d_in[1];
  const int*   seqlen = (const int*)  d_in[2];
  const int*   repw   = (const int*)  d_in[3];
  const int*   valid  = (const int*)  d_in[4];
  const float* emb    = (const float*)d_in[5];
  const float* enc    = (const float*)d_in[6];
  const float* Wih0   = (const float*)d_in[7];
  const float* Whh0   = (const float*)d_in[8];
  const float* b0     = (const float*)d_in[9];
  const float* Wih1   = (const float*)d_in[10];
  const float* Whh1   = (const float*)d_in[11];
  const float* b1     = (const float*)d_in[12];
  const float* delv   = (const float*)d_in[13];
  const float* holdv  = (const float*)d_in[14];
  const float* mW     = (const float*)d_in[15];
  const float* mb     = (const float*)d_in[16];
  const float* m1W    = (const float*)d_in[17];
  const float* m1b    = (const float*)d_in[18];
  float* out = (float*)d_out;

  char* ws = (char*)d_ws;
  size_t off = 0;
  auto allocB = [&](size_t bytes) -> char* {
    char* pp = ws + off; off += (bytes + 255) & ~size_t(255); return pp;
  };
  f16*  Wp0h = (f16*)allocB((size_t)2*2048*1040*2);
  f16*  Wp0l = (f16*)allocB((size_t)2*2048*1040*2);
  f16*  Wp1h = (f16*)allocB((size_t)2*2048*1536*2);
  f16*  Wp1l = (f16*)allocB((size_t)2*2048*1536*2);
  float* bp0 = (float*)allocB(4096*4);
  float* bp1 = (float*)allocB(4096*4);
  float* mWt = (float*)allocB(104000*4);
  float* ep  = (float*)allocB((size_t)30007*100*4);
  int* stbuf  = (int*)allocB(B_*L_*4);
  int* lenbuf = (int*)allocB(B_*4);
  size_t fixedB = off;

  // pick largest chunk size that fits
  const int cands[6] = {4096, 2048, 1024, 512, 256, 128};
  int Bc = 0;
  for (int ci=0; ci<6; ++ci){
    size_t c = cands[ci];
    size_t chunkB = c*(size_t)(2*528*2*2 + 15*1024*2*2 + 4*512*2*2 + 2*512*4*2 + 1024*4) + 12*256;
    if (fixedB + chunkB <= ws_size){ Bc = (int)c; break; }
  }
  if (!Bc){
    float code = 100000.0f + (float)(ws_size >> 20);
    sentinel<<<(B_*NSTEP_+255)/256,256,0,stream>>>(out, code);
    return;
  }
  f16* X2h = (f16*)allocB((size_t)2*Bc*528*2);
  f16* X2l = (f16*)allocB((size_t)2*Bc*528*2);
  f16* o0h = (f16*)allocB((size_t)L_*Bc*1024*2);
  f16* o0l = (f16*)allocB((size_t)L_*Bc*1024*2);
  f16* h1h = (f16*)allocB((size_t)4*Bc*512*2);
  f16* h1l = (f16*)allocB((size_t)4*Bc*512*2);
  float* c0 = (float*)allocB((size_t)2*Bc*512*4);
  float* c1 = (float*)allocB((size_t)2*Bc*512*4);
  float* pooled = (float*)allocB((size_t)Bc*1024*4);

  prep_w0<<<(2*2048*1040+255)/256,256,0,stream>>>(Wih0, Whh0, b0, Wp0h, Wp0l, bp0);
  prep_w1<<<(2*2048*1536+255)/256,256,0,stream>>>(Wih1, Whh1, b1, Wp1h, Wp1l, bp1);
  prep_mlpwt<<<(100*1040+255)/256,256,0,stream>>>(mW, mWt);
  prep_encproj<<<30007,128,0,stream>>>(enc, delv, holdv, m1W, m1b, ep);
  init_st<<<(B_*L_+255)/256,256,0,stream>>>(ids, seqlen, stbuf, lenbuf);

  for (int b0c=0; b0c<B_; b0c+=Bc){
    for (int step=0; step<NSTEP_; ++step){
      int pos = step + 2;   // i % 12 + 2 for i=0..4

      // ---- layer 0: full 15 timesteps, fw (t=ts) + bw (t=14-ts)
      for (int ts=0; ts<L_; ++ts){
        int tf = ts, tb = 14-ts;
        build_x2<<<(2*Bc*132+255)/256,256,0,stream>>>(stbuf, ids, emb, X2h, X2l, pos, tf, tb, b0c, Bc);
        RecParams p{};
        p.A1h_0 = X2h;                    p.A1l_0 = X2l;
        p.A1h_1 = X2h + (size_t)Bc*528;   p.A1l_1 = X2l + (size_t)Bc*528;
        p.lda1 = 528; p.k1t = 33;
        p.k2t  = ts ? 32 : 0;
        size_t of0 = (size_t)(ts?tf-1:0)*Bc*1024;
        size_t of1 = (size_t)(ts?tb+1:0)*Bc*1024 + (ts?512:0);
        p.A2h_0 = o0h + of0;  p.A2l_0 = o0l + of0;
        p.A2h_1 = o0h + of1;  p.A2l_1 = o0l + of1;
        p.lda2 = 1024;
        p.Wh_0 = Wp0h; p.Wl_0 = Wp0l;
        p.Wh_1 = Wp0h + (size_t)2048*1040; p.Wl_1 = Wp0l + (size_t)2048*1040;
        p.ldw = 1040;
        p.bias_0 = bp0; p.bias_1 = bp0 + 2048;
        p.c_0 = c0; p.c_1 = c0 + (size_t)Bc*512;
        p.hh_0 = o0h + (size_t)tf*Bc*1024;       p.hl_0 = o0l + (size_t)tf*Bc*1024;
        p.hh_1 = o0h + (size_t)tb*Bc*1024 + 512; p.hl_1 = o0l + (size_t)tb*Bc*1024 + 512;
        p.ldh = 1024;
        p.h2_0 = nullptr; p.h2_1 = nullptr; p.ldh2 = 1024;
        p.first = (ts==0); p.act0 = 1; p.act1 = 1;
        rec_gemm<<<dim3(16,Bc/128,2),256,0,stream>>>(p);
      }

      // ---- layer 1: fw needs t<=pos only, bw needs t>=pos only
      int nL1 = L_ - pos;
      for (int ts=0; ts<nL1; ++ts){
        RecParams p{};
        int tf = ts, tb = 14-ts;
        int parR = (ts-1)&1, parW = ts&1;
        p.A1h_0 = o0h + (size_t)tf*Bc*1024;  p.A1l_0 = o0l + (size_t)tf*Bc*1024;
        p.A1h_1 = o0h + (size_t)tb*Bc*1024;  p.A1l_1 = o0l + (size_t)tb*Bc*1024;
        p.lda1 = 1024; p.k1t = 64;
        p.k2t  = ts ? 32 : 0;
        size_t r0 = (size_t)(0*2 + (ts?parR:0))*Bc*512;
        size_t r1 = (size_t)(1*2 + (ts?parR:0))*Bc*512;
        p.A2h_0 = h1h + r0; p.A2l_0 = h1l + r0;
        p.A2h_1 = h1h + r1; p.A2l_1 = h1l + r1;
        p.lda2 = 512;
        p.Wh_0 = Wp1h; p.Wl_0 = Wp1l;
        p.Wh_1 = Wp1h + (size_t)2048*1536; p.Wl_1 = Wp1l + (size_t)2048*1536;
        p.ldw = 1536;
        p.bias_0 = bp1; p.bias_1 = bp1 + 2048;
        p.c_0 = c1; p.c_1 = c1 + (size_t)Bc*512;
        size_t w0 = (size_t)(0*2 + parW)*Bc*512;
        size_t w1 = (size_t)(1*2 + parW)*Bc*512;
        p.hh_0 = h1h + w0; p.hl_0 = h1l + w0;
        p.hh_1 = h1h + w1; p.hl_1 = h1l + w1;
        p.ldh = 512;
        p.h2_0 = (ts == pos)    ? pooled        : nullptr;
        p.h2_1 = (ts == 14-pos) ? (pooled+512)  : nullptr;
        p.ldh2 = 1024;
        p.first = (ts==0);
        p.act0 = (ts <= pos) ? 1 : 0; p.act1 = 1;
        rec_gemm<<<dim3(16,Bc/128,2),256,0,stream>>>(p);
      }

      score_update<<<Bc,128,0,stream>>>(pooled, keypos, mWt, mb, ep, m1W, repw, valid,
                                        stbuf, lenbuf, out, out + B_*NSTEP_, step, pos, b0c);
    }
  }
  finalize<<<(B_*L_+B_+255)/256,256,0,stream>>>(stbuf, lenbuf, out);
}

// Round 6
// 18515.535 us; speedup vs baseline: 1.3560x; 1.3560x over previous
//
#include <hip/hip_runtime.h>

#define B_ 4096
#define L_ 15
#define NSTEP_ 5
#define VOC_ 30005
#define PAD_ 30003

typedef _Float16 f16;
typedef f16  f16x8 __attribute__((ext_vector_type(8)));
typedef float f32x16 __attribute__((ext_vector_type(16)));

__device__ __forceinline__ float sigf(float x){ return 1.0f/(1.0f+expf(-x)); }

#define MFMA_(d,a,b) d = __builtin_amdgcn_mfma_f32_32x32x16_f16(a,b,d,0,0,0)

// ---------------------------------------------------------------- params
struct RecParams {
  const f16 *A1h_0,*A1l_0,*A1h_1,*A1l_1;   // x-part arrays (layer1 path)
  const f16 *A2h_0,*A2l_0,*A2h_1,*A2l_1;   // h-part arrays
  const f16 *Wfh_0,*Wfl_0,*Wfh_1,*Wfl_1;   // fragment-order W
  const float *bias_0,*bias_1;
  const f16 *embH,*embL;                   // split emb table (gather mode)
  const int *st,*ids;
  float *c_0,*c_1,*h2_0,*h2_1;
  f16 *hh_0,*hl_0,*hh_1,*hl_1;
  int lda1, lda2, ldh, ldh2, k1p, k2p, first, gather, t_0, t_1, pos, b0c, act0, act1;
};

// swizzled byte offset into a [128 rows][16 k] f16 (4KB) LDS array.
// unit u = 2r+s (r=row&7) -> u' = u ^ (u>>1)  (Gray): bijective, spreads
// same-s reads across 8 distinct 16B slots -> near-conflict-free b128.
__device__ __forceinline__ int swz(int row, int s){
  int u = ((row&7)<<1) | s;
  return ((row>>3)<<8) + ((u ^ (u>>1))<<4);
}

// --------------------------------- fused split-f16 MFMA GEMM + LSTM cell
// C(Bc x 2048) = A(Bc x K) @ W^T (+bias); A,W as (hi, lo*2^12) f16 pairs.
// 3 MFMA passes: accM += Ah*Wh; accX += Ah*Wl + Al*Wh; z = accM + 2^-12*accX.
// BK=32 (2 kt16 sub-tiles per phase). B-fragments load DIRECTLY from global
// (fragment-linear Wf layout) -> LDS stages A only. Layer-0 x-part gathered
// in-kernel from split emb tables (embt zero at t==pos, posflag at col 512).
__global__ __launch_bounds__(256,2) void rec_gemm(RecParams p){
  const int dir = blockIdx.z;
  if (!(dir ? p.act1 : p.act0)) return;
  const f16* A1h = dir ? p.A1h_1 : p.A1h_0;
  const f16* A1l = dir ? p.A1l_1 : p.A1l_0;
  const f16* A2h = dir ? p.A2h_1 : p.A2h_0;
  const f16* A2l = dir ? p.A2l_1 : p.A2l_0;
  const f16* Wfh = dir ? p.Wfh_1 : p.Wfh_0;
  const f16* Wfl = dir ? p.Wfl_1 : p.Wfl_0;
  const float* bias = dir ? p.bias_1 : p.bias_0;
  float* cbuf = dir ? p.c_1 : p.c_0;
  float* h2   = dir ? p.h2_1 : p.h2_0;
  f16* hhb = dir ? p.hh_1 : p.hh_0;
  f16* hlb = dir ? p.hl_1 : p.hl_0;
  const int tcur = dir ? p.t_1 : p.t_0;

  const int tid  = threadIdx.x;
  const int lane = tid & 63;
  const int w    = tid >> 6;
  const int mbase = blockIdx.y*128;

  __shared__ union {
    float z[128*128];          // 64 KB epilogue
    f16   stg[8][2048];        // [buf*4 + {Ah_s0,Al_s0,Ah_s1,Al_s1}] 4KB each
  } sm;

  f32x16 accM[2][2], accX[2][2];
#pragma unroll
  for (int i=0;i<2;i++)
#pragma unroll
    for (int j=0;j<2;j++)
#pragma unroll
      for (int r=0;r<16;r++){ accM[i][j][r]=0.f; accX[i][j][r]=0.f; }

  // a-frag read offsets (validated R4 scheme, per 4KB sub-array)
  const int arow = (w&1)*64 + (lane&31);
  const int fs = lane>>5;
  const int aoff0 = swz(arow,    fs), aoff1 = swz(arow+32, fs);

  // b-frag global fragment pointers
  const int ct0 = blockIdx.x*4 + (w>>1)*2;
  const f16* WfhL = Wfh + (size_t)lane*8;
  const f16* WflL = Wfl + (size_t)lane*8;

  // A staging: thread stages unit (srow, ss) for 4 arrays
  const int srow = tid >> 1, ss = tid & 1;
  const int sws = swz(srow, ss);
  const int ktot = p.k1p + p.k2p;

  // gather-mode hoisted tokens
  int tokT=0, tokI=0, zflag=0;
  if (p.gather){
    int gb = p.b0c + mbase + srow;
    tokT = p.st [gb*L_ + tcur];
    tokI = p.ids[gb*L_ + tcur];
    zflag = (tcur == p.pos) ? 1 : 0;
  }

  f16x8 ra_h0, ra_l0, ra_h1, ra_l1;
  const f16x8 zero8 = {0,0,0,0,0,0,0,0};

  auto gload = [&](int ph){
    if (ph >= ktot) return;
    if (ph < p.k1p){
      if (p.gather){
        if (ph < 8){                     // embt part (cols 0..255)
          if (zflag){ ra_h0=zero8; ra_l0=zero8; ra_h1=zero8; ra_l1=zero8; }
          else {
            size_t base = (size_t)tokT*256 + ph*32 + ss*8;
            ra_h0 = *(const f16x8*)(p.embH + base);
            ra_l0 = *(const f16x8*)(p.embL + base);
            ra_h1 = *(const f16x8*)(p.embH + base + 16);
            ra_l1 = *(const f16x8*)(p.embL + base + 16);
          }
        } else if (ph < 16){             // emb0 part (cols 256..511)
          size_t base = (size_t)tokI*256 + (ph-8)*32 + ss*8;
          ra_h0 = *(const f16x8*)(p.embH + base);
          ra_l0 = *(const f16x8*)(p.embL + base);
          ra_h1 = *(const f16x8*)(p.embH + base + 16);
          ra_l1 = *(const f16x8*)(p.embL + base + 16);
        } else {                         // ph==16: posflag @512, rest 0
          ra_h0 = zero8; ra_l0 = zero8; ra_h1 = zero8; ra_l1 = zero8;
          if (ss == 0) ra_h0[0] = zflag ? (f16)1.0f : (f16)0.0f;
        }
      } else {
        long base = (long)(mbase+srow)*p.lda1 + ph*32 + ss*8;
        ra_h0 = *(const f16x8*)(A1h + base);
        ra_l0 = *(const f16x8*)(A1l + base);
        ra_h1 = *(const f16x8*)(A1h + base + 16);
        ra_l1 = *(const f16x8*)(A1l + base + 16);
      }
    } else {
      long base = (long)(mbase+srow)*p.lda2 + (ph - p.k1p)*32 + ss*8;
      ra_h0 = *(const f16x8*)(A2h + base);
      ra_l0 = *(const f16x8*)(A2l + base);
      ra_h1 = *(const f16x8*)(A2h + base + 16);
      ra_l1 = *(const f16x8*)(A2l + base + 16);
    }
  };
  auto swrite = [&](int buf){
    *(f16x8*)((char*)sm.stg[buf*4+0] + sws) = ra_h0;
    *(f16x8*)((char*)sm.stg[buf*4+1] + sws) = ra_l0;
    *(f16x8*)((char*)sm.stg[buf*4+2] + sws) = ra_h1;
    *(f16x8*)((char*)sm.stg[buf*4+3] + sws) = ra_l1;
  };

  gload(0); swrite(0); gload(1);
  __syncthreads();

  for (int ph=0; ph<ktot; ++ph){
    const int cur = ph & 1;
    // B fragments for this phase (global, L1/L2-resident)
    size_t base0 = ((size_t)(ph*2+0)*64 + ct0)*512;
    size_t base1 = ((size_t)(ph*2+1)*64 + ct0)*512;
    f16x8 rbh00 = *(const f16x8*)(WfhL + base0);
    f16x8 rbh01 = *(const f16x8*)(WfhL + base0 + 512);
    f16x8 rbl00 = *(const f16x8*)(WflL + base0);
    f16x8 rbl01 = *(const f16x8*)(WflL + base0 + 512);
    f16x8 rbh10 = *(const f16x8*)(WfhL + base1);
    f16x8 rbh11 = *(const f16x8*)(WfhL + base1 + 512);
    f16x8 rbl10 = *(const f16x8*)(WflL + base1);
    f16x8 rbl11 = *(const f16x8*)(WflL + base1 + 512);
    // A fragments from LDS
    const char* s0h = (const char*)sm.stg[cur*4+0];
    const char* s0l = (const char*)sm.stg[cur*4+1];
    const char* s1h = (const char*)sm.stg[cur*4+2];
    const char* s1l = (const char*)sm.stg[cur*4+3];
    f16x8 a00h = *(const f16x8*)(s0h + aoff0);
    f16x8 a01h = *(const f16x8*)(s0h + aoff1);
    f16x8 a00l = *(const f16x8*)(s0l + aoff0);
    f16x8 a01l = *(const f16x8*)(s0l + aoff1);
    f16x8 a10h = *(const f16x8*)(s1h + aoff0);
    f16x8 a11h = *(const f16x8*)(s1h + aoff1);
    f16x8 a10l = *(const f16x8*)(s1l + aoff0);
    f16x8 a11l = *(const f16x8*)(s1l + aoff1);
    // stage next tile, issue loads for ph+2 (latency hides under MFMA)
    if (ph+1 < ktot){ swrite((ph+1)&1); gload(ph+2); }
    // sub0
    MFMA_(accM[0][0], a00h, rbh00); MFMA_(accX[0][0], a00h, rbl00); MFMA_(accX[0][0], a00l, rbh00);
    MFMA_(accM[1][0], a01h, rbh00); MFMA_(accX[1][0], a01h, rbl00); MFMA_(accX[1][0], a01l, rbh00);
    MFMA_(accM[0][1], a00h, rbh01); MFMA_(accX[0][1], a00h, rbl01); MFMA_(accX[0][1], a00l, rbh01);
    MFMA_(accM[1][1], a01h, rbh01); MFMA_(accX[1][1], a01h, rbl01); MFMA_(accX[1][1], a01l, rbh01);
    // sub1
    MFMA_(accM[0][0], a10h, rbh10); MFMA_(accX[0][0], a10h, rbl10); MFMA_(accX[0][0], a10l, rbh10);
    MFMA_(accM[1][0], a11h, rbh10); MFMA_(accX[1][0], a11h, rbl10); MFMA_(accX[1][0], a11l, rbh10);
    MFMA_(accM[0][1], a10h, rbh11); MFMA_(accX[0][1], a10h, rbl11); MFMA_(accX[0][1], a10l, rbh11);
    MFMA_(accM[1][1], a11h, rbh11); MFMA_(accX[1][1], a11h, rbl11); MFMA_(accX[1][1], a11l, rbh11);
    __syncthreads();
  }

  // ---- epilogue: z tiles -> LDS (regroup gates), then fused LSTM cell
#pragma unroll
  for (int tm=0;tm<2;tm++)
#pragma unroll
   for (int tn=0;tn<2;tn++){
    int lcol = (w>>1)*64 + tn*32 + (lane&31);
    float bv = bias[blockIdx.x*128 + lcol];
#pragma unroll
    for (int r=0;r<16;r++){
      int lrow = (w&1)*64 + tm*32 + (r&3) + 8*(r>>2) + 4*(lane>>5);
      sm.z[lrow*128 + lcol] = accM[tm][tn][r] + 0.000244140625f*accX[tm][tn][r] + bv;
    }
   }
  __syncthreads();

  const int nb = blockIdx.x*32;   // hidden-unit base for this block
#pragma unroll
  for (int it=0; it<16; ++it){
    int idx = it*256 + tid;
    int nq = idx & 31, row = idx >> 5;
    float4 g4 = *(const float4*)&sm.z[row*128 + nq*4];
    int m = mbase + row, n = nb + nq;
    float cp = p.first ? 0.f : cbuf[(size_t)m*512 + n];
    float cc = sigf(g4.y)*cp + sigf(g4.x)*tanhf(g4.z);
    float hv = sigf(g4.w)*tanhf(cc);
    cbuf[(size_t)m*512 + n] = cc;
    f16 hi = (f16)hv;
    f16 lo = (f16)((hv - (float)hi)*4096.0f);
    hhb[(size_t)m*p.ldh + n] = hi;
    hlb[(size_t)m*p.ldh + n] = lo;
    if (h2) h2[(size_t)m*p.ldh2 + n] = hv;
  }
}

// ------------------------------------------- prep: W in MFMA fragment order
// Wf index = (((dir*NK16 + kt16)*64 + ct)*64 + lane)*8 + j
// content  = W'[ct*32 + (lane&31)][kt16*16 + (lane>>5)*8 + j], W' row-permuted n*4+gate.
__global__ void prep_w0(const float* Wih, const float* Whh, const float* b0,
                        f16* Wfh, f16* Wfl, float* bp){
  int gid = blockIdx.x*blockDim.x + threadIdx.x;
  const int PER_DIR = 66*64*64*8;
  if (gid >= 2*PER_DIR) return;
  int dir = gid / PER_DIR;
  int rem = gid % PER_DIR;
  int j = rem & 7, lane = (rem>>3)&63, ct = (rem>>9)&63, kt16 = rem>>15;
  int n4g = ct*32 + (lane&31);
  int n = n4g>>2, g = n4g&3;
  int srow = dir*2048 + g*512 + n;
  int k = kt16*16 + ((lane>>5)<<3) + j;     // padded K: [Wih 513 | pad 31 | Whh 512]
  float v;
  if (k < 513)       v = Wih[(size_t)srow*513 + k];
  else if (k < 544)  v = 0.f;
  else               v = Whh[(size_t)srow*512 + (k-544)];
  f16 hi = (f16)v;
  Wfh[gid] = hi;
  Wfl[gid] = (f16)((v - (float)hi)*4096.0f);
  if (kt16==0 && (lane>>5)==0 && j==0) bp[dir*2048 + n4g] = b0[srow];
}

__global__ void prep_w1(const float* Wih, const float* Whh, const float* b1,
                        f16* Wfh, f16* Wfl, float* bp){
  int gid = blockIdx.x*blockDim.x + threadIdx.x;
  const int PER_DIR = 96*64*64*8;
  if (gid >= 2*PER_DIR) return;
  int dir = gid / PER_DIR;
  int rem = gid % PER_DIR;
  int j = rem & 7, lane = (rem>>3)&63, ct = (rem>>9)&63, kt16 = rem>>15;
  int n4g = ct*32 + (lane&31);
  int n = n4g>>2, g = n4g&3;
  int srow = dir*2048 + g*512 + n;
  int k = kt16*16 + ((lane>>5)<<3) + j;     // [Wih 1024 | Whh 512]
  float v;
  if (k < 1024) v = Wih[(size_t)srow*1024 + k];
  else          v = Whh[(size_t)srow*512 + (k-1024)];
  f16 hi = (f16)v;
  Wfh[gid] = hi;
  Wfl[gid] = (f16)((v - (float)hi)*4096.0f);
  if (kt16==0 && (lane>>5)==0 && j==0) bp[dir*2048 + n4g] = b1[srow];
}

__global__ void prep_emb(const float* emb, f16* eh, f16* el){
  int gid = blockIdx.x*blockDim.x + threadIdx.x;
  if (gid >= VOC_*256) return;
  float v = emb[gid];
  f16 hi = (f16)v;
  eh[gid] = hi;
  el[gid] = (f16)((v - (float)hi)*4096.0f);
}

__global__ void prep_mlpwt(const float* mW, float* wt){
  int gid = blockIdx.x*blockDim.x + threadIdx.x;
  if (gid >= 100*1040) return;
  int j = gid / 1040, k = gid % 1040;
  wt[k*100 + j] = mW[gid];
}

__global__ __launch_bounds__(128) void prep_encproj(const float* enc, const float* delv,
                        const float* holdv, const float* m1W, const float* m1b, float* ep){
  int r = blockIdx.x;
  __shared__ float row[256];
  const float* src = (r < VOC_) ? enc + (size_t)r*256 : (r == VOC_ ? delv : holdv);
  for (int i=threadIdx.x;i<256;i+=128) row[i]=src[i];
  __syncthreads();
  int j = threadIdx.x;
  if (j < 100){
    double s = (double)m1b[j];
    const float* wr = m1W + (size_t)j*298;
    for (int k=0;k<256;k++) s += (double)wr[k] * (double)row[k];
    ep[(size_t)r*100 + j] = (float)s;
  }
}

__global__ void init_st(const int* ids, const int* seqlen, int* st, int* len){
  int gid = blockIdx.x*blockDim.x + threadIdx.x;
  if (gid < B_*L_) st[gid] = ids[gid];
  if (gid < B_)    len[gid] = seqlen[gid];
}

__global__ void sentinel(float* out, float v){
  int gid = blockIdx.x*blockDim.x + threadIdx.x;
  if (gid < B_*NSTEP_) out[gid] = v;
}

// ------------------------------------------------- scoring + sequence edit
__global__ __launch_bounds__(128) void score_update(
    const float* pooled, const float* keypos, const float* mWt, const float* mb,
    const float* ep, const float* m1W, const int* repw, const int* valid,
    int* st, int* len, float* outPis, float* outActs, int step, int pos, int b0){
  int b = blockIdx.x;
  int bg = b0 + b;
  __shared__ float rep[1040];
  __shared__ float r100[100];
  __shared__ double sc[42];
  int tid = threadIdx.x;
  for (int i=tid;i<1024;i+=128) rep[i] = pooled[(size_t)b*1024+i];
  if (tid < 16){
    if (tid == 0) rep[1024] = keypos[bg*L_+pos];
    else          rep[1024+tid] = ((tid-1)==pos) ? 1.f : 0.f;
  }
  __syncthreads();
  if (tid < 100){
    double s = (double)mb[tid];
    for (int k=0;k<1040;k++) s += (double)mWt[k*100+tid] * (double)rep[k];
    r100[tid] = (float)s;
  }
  __syncthreads();
  if (tid < 42){
    int row = (tid < 40) ? repw[((size_t)bg*NSTEP_+step)*40 + tid] : (VOC_ + (tid-40));
    const float* er = ep + (size_t)row*100;
    double s = 0.0;
    for (int j=0;j<100;j++) s += (double)er[j] * (double)r100[j];
    for (int j=0;j<100;j++) s += (double)m1W[j*298 + 256 + tid] * (double)r100[j];
    sc[tid] = s;
  }
  __syncthreads();
  if (tid == 0){
    double mx = sc[0]; int am = 0;
    for (int k=1;k<42;k++) if (sc[k] > mx){ mx = sc[k]; am = k; }
    double sum = 0.0;
    for (int k=0;k<42;k++) sum += exp(sc[k]-mx);
    float pi = (float)(1.0/sum);
    int vid = valid[bg*NSTEP_+step];
    int ln  = len[bg];
    int repb = (am < 20) ? 1 : 0;
    int insb = (am >= 20 && am < 40) ? 1 : 0;
    int delb = (am == 40) ? 1 : 0;
    int repf = repb*vid;
    int insf = insb*vid*(((ln+insb) <= 15) ? 1 : 0);
    int delf = delb*vid*(((ln-delb) >  2) ? 1 : 0);
    int T = L_ - pos;
    int tail[13];
    for (int j=0;j<T;j++) tail[j] = st[bg*L_+pos+j];
    int aw = repw[((size_t)bg*NSTEP_+step)*40 + (am < 20 ? am : 19)];
    for (int j=0;j<T;j++){
      int rv = (j==0) ? aw : tail[j];
      int iv = (j==0) ? aw : tail[j-1];
      int dv = (j < T-1) ? tail[j+1] : PAD_;
      int hv = tail[j];
      int nv = repf ? rv : (insf ? iv : (delf ? dv : hv));
      st[bg*L_+pos+j] = nv;
    }
    len[bg] = ln + insf - delf;
    outPis[bg*NSTEP_+step]  = pi;
    outActs[bg*NSTEP_+step] = (float)am;
  }
}

__global__ void finalize(const int* st, const int* len, float* out){
  int gid = blockIdx.x*blockDim.x + threadIdx.x;
  if (gid < B_*L_)            out[2*B_*NSTEP_ + gid] = (float)st[gid];
  else if (gid < B_*L_ + B_)  out[2*B_*NSTEP_ + B_*L_ + (gid - B_*L_)] = (float)len[gid - B_*L_];
}

// ---------------------------------------------------------------- launch
extern "C" void kernel_launch(void* const* d_in, const int* in_sizes, int n_in,
                              void* d_out, int out_size, void* d_ws, size_t ws_size,
                              hipStream_t stream) {
  const int*   ids    = (const int*)  d_in[0];
  const float* keypos = (const float*)d_in[1];
  const int*   seqlen = (const int*)  d_in[2];
  const int*   repw   = (const int*)  d_in[3];
  const int*   valid  = (const int*)  d_in[4];
  const float* emb    = (const float*)d_in[5];
  const float* enc    = (const float*)d_in[6];
  const float* Wih0   = (const float*)d_in[7];
  const float* Whh0   = (const float*)d_in[8];
  const float* b0     = (const float*)d_in[9];
  const float* Wih1   = (const float*)d_in[10];
  const float* Whh1   = (const float*)d_in[11];
  const float* b1     = (const float*)d_in[12];
  const float* delv   = (const float*)d_in[13];
  const float* holdv  = (const float*)d_in[14];
  const float* mW     = (const float*)d_in[15];
  const float* mb     = (const float*)d_in[16];
  const float* m1W    = (const float*)d_in[17];
  const float* m1b    = (const float*)d_in[18];
  float* out = (float*)d_out;

  const int NKW0 = 66, NKW1 = 96;
  const size_t W0PD = (size_t)NKW0*64*64*8;   // f16 per dir
  const size_t W1PD = (size_t)NKW1*64*64*8;

  char* ws = (char*)d_ws;
  size_t off = 0;
  auto allocB = [&](size_t bytes) -> char* {
    char* pp = ws + off; off += (bytes + 255) & ~size_t(255); return pp;
  };
  f16*  Wf0h = (f16*)allocB(2*W0PD*2);
  f16*  Wf0l = (f16*)allocB(2*W0PD*2);
  f16*  Wf1h = (f16*)allocB(2*W1PD*2);
  f16*  Wf1l = (f16*)allocB(2*W1PD*2);
  float* bp0 = (float*)allocB(4096*4);
  float* bp1 = (float*)allocB(4096*4);
  f16*  embH = (f16*)allocB((size_t)VOC_*256*2);
  f16*  embL = (f16*)allocB((size_t)VOC_*256*2);
  float* mWt = (float*)allocB(104000*4);
  float* ep  = (float*)allocB((size_t)30007*100*4);
  int* stbuf  = (int*)allocB(B_*L_*4);
  int* lenbuf = (int*)allocB(B_*4);
  size_t fixedB = off;

  // pick largest chunk size that fits (per-row: 81920 B)
  const int cands[6] = {4096, 2048, 1024, 512, 256, 128};
  int Bc = 0;
  for (int ci=0; ci<6; ++ci){
    size_t c = cands[ci];
    size_t chunkB = c*(size_t)(15*1024*2*2 + 4*512*2*2 + 2*512*4 + 2*512*4 + 1024*4) + 8*256;
    if (fixedB + chunkB <= ws_size){ Bc = (int)c; break; }
  }
  if (!Bc){
    float code = 100000.0f + (float)(ws_size >> 20);
    sentinel<<<(B_*NSTEP_+255)/256,256,0,stream>>>(out, code);
    return;
  }
  f16* o0h = (f16*)allocB((size_t)L_*Bc*1024*2);
  f16* o0l = (f16*)allocB((size_t)L_*Bc*1024*2);
  f16* h1h = (f16*)allocB((size_t)4*Bc*512*2);
  f16* h1l = (f16*)allocB((size_t)4*Bc*512*2);
  float* c0 = (float*)allocB((size_t)2*Bc*512*4);
  float* c1 = (float*)allocB((size_t)2*Bc*512*4);
  float* pooled = (float*)allocB((size_t)Bc*1024*4);

  prep_w0<<<(int)((2*W0PD+255)/256),256,0,stream>>>(Wih0, Whh0, b0, Wf0h, Wf0l, bp0);
  prep_w1<<<(int)((2*W1PD+255)/256),256,0,stream>>>(Wih1, Whh1, b1, Wf1h, Wf1l, bp1);
  prep_emb<<<(VOC_*256+255)/256,256,0,stream>>>(emb, embH, embL);
  prep_mlpwt<<<(100*1040+255)/256,256,0,stream>>>(mW, mWt);
  prep_encproj<<<30007,128,0,stream>>>(enc, delv, holdv, m1W, m1b, ep);
  init_st<<<(B_*L_+255)/256,256,0,stream>>>(ids, seqlen, stbuf, lenbuf);

  for (int b0c=0; b0c<B_; b0c+=Bc){
    for (int step=0; step<NSTEP_; ++step){
      int pos = step + 2;   // i % 12 + 2 for i=0..4

      // ---- layer 0: full 15 timesteps, fw (t=ts) + bw (t=14-ts)
      for (int ts=0; ts<L_; ++ts){
        int tf = ts, tb = 14-ts;
        RecParams p{};
        p.gather = 1; p.t_0 = tf; p.t_1 = tb; p.pos = pos; p.b0c = b0c;
        p.embH = embH; p.embL = embL; p.st = stbuf; p.ids = ids;
        p.k1p = 17; p.k2p = ts ? 16 : 0;
        size_t of0 = (size_t)(ts?tf-1:0)*Bc*1024;
        size_t of1 = (size_t)(ts?tb+1:0)*Bc*1024 + (ts?512:0);
        p.A2h_0 = o0h + of0;  p.A2l_0 = o0l + of0;
        p.A2h_1 = o0h + of1;  p.A2l_1 = o0l + of1;
        p.lda2 = 1024;
        p.Wfh_0 = Wf0h;        p.Wfl_0 = Wf0l;
        p.Wfh_1 = Wf0h + W0PD; p.Wfl_1 = Wf0l + W0PD;
        p.bias_0 = bp0; p.bias_1 = bp0 + 2048;
        p.c_0 = c0; p.c_1 = c0 + (size_t)Bc*512;
        p.hh_0 = o0h + (size_t)tf*Bc*1024;       p.hl_0 = o0l + (size_t)tf*Bc*1024;
        p.hh_1 = o0h + (size_t)tb*Bc*1024 + 512; p.hl_1 = o0l + (size_t)tb*Bc*1024 + 512;
        p.ldh = 1024;
        p.h2_0 = nullptr; p.h2_1 = nullptr; p.ldh2 = 1024;
        p.first = (ts==0); p.act0 = 1; p.act1 = 1;
        rec_gemm<<<dim3(16,Bc/128,2),256,0,stream>>>(p);
      }

      // ---- layer 1: fw needs t<=pos only, bw needs t>=pos only
      int nL1 = L_ - pos;
      for (int ts=0; ts<nL1; ++ts){
        RecParams p{};
        int tf = ts, tb = 14-ts;
        int parR = (ts-1)&1, parW = ts&1;
        p.gather = 0;
        p.A1h_0 = o0h + (size_t)tf*Bc*1024;  p.A1l_0 = o0l + (size_t)tf*Bc*1024;
        p.A1h_1 = o0h + (size_t)tb*Bc*1024;  p.A1l_1 = o0l + (size_t)tb*Bc*1024;
        p.lda1 = 1024; p.k1p = 32;
        p.k2p  = ts ? 16 : 0;
        size_t r0 = (size_t)(0*2 + (ts?parR:0))*Bc*512;
        size_t r1 = (size_t)(1*2 + (ts?parR:0))*Bc*512;
        p.A2h_0 = h1h + r0; p.A2l_0 = h1l + r0;
        p.A2h_1 = h1h + r1; p.A2l_1 = h1l + r1;
        p.lda2 = 512;
        p.Wfh_0 = Wf1h;        p.Wfl_0 = Wf1l;
        p.Wfh_1 = Wf1h + W1PD; p.Wfl_1 = Wf1l + W1PD;
        p.bias_0 = bp1; p.bias_1 = bp1 + 2048;
        p.c_0 = c1; p.c_1 = c1 + (size_t)Bc*512;
        size_t w0 = (size_t)(0*2 + parW)*Bc*512;
        size_t w1 = (size_t)(1*2 + parW)*Bc*512;
        p.hh_0 = h1h + w0; p.hl_0 = h1l + w0;
        p.hh_1 = h1h + w1; p.hl_1 = h1l + w1;
        p.ldh = 512;
        p.h2_0 = (ts == pos)    ? pooled        : nullptr;
        p.h2_1 = (ts == 14-pos) ? (pooled+512)  : nullptr;
        p.ldh2 = 1024;
        p.first = (ts==0);
        p.act0 = (ts <= pos) ? 1 : 0; p.act1 = 1;
        rec_gemm<<<dim3(16,Bc/128,2),256,0,stream>>>(p);
      }

      score_update<<<Bc,128,0,stream>>>(pooled, keypos, mWt, mb, ep, m1W, repw, valid,
                                        stbuf, lenbuf, out, out + B_*NSTEP_, step, pos, b0c);
    }
  }
  finalize<<<(B_*L_+B_+255)/256,256,0,stream>>>(stbuf, lenbuf, out);
}